// Round 2
// baseline (53.938 us; speedup 1.0000x reference)
//
#include <hip/hip_runtime.h>

typedef __attribute__((ext_vector_type(8))) short short8;
typedef __attribute__((ext_vector_type(4))) float f32x4;

#define DI __device__ __forceinline__

namespace {
constexpr int TOT_ = 512;   // output row width (floats)
constexpr int XROW = 2048;  // x row width (floats) = F*D
constexpr int NB_  = 2048;  // (16384/64 rows) * 8 feature-groups
}

DI unsigned short f2bf(float v) {
    __bf16 h = (__bf16)v;                      // RNE convert
    return __builtin_bit_cast(unsigned short, h);
}

__global__ __launch_bounds__(512)
void recon_kernel(const float* __restrict__ x, const float* __restrict__ W1,
                  const float* __restrict__ b1, const float* __restrict__ W2,
                  const float* __restrict__ b2, float* __restrict__ out)
{
    // 48 KB LDS union:
    //  [0..16384) shorts : phase A/B weight staging (32 KB), later out_lds [64][124] f32 (31 KB)
    //  [16384..24576)    : per-wave h staging, 1024 shorts each (16 KB)
    __shared__ __align__(16) unsigned short u_sm[24576];

    // XCD-aware remap: xcd owns rowtiles [xcd*32, xcd*32+32); fg cycles fastest so
    // co-resident blocks on an XCD cover full 8-KB x rows and merge out boundary lines.
    const int bid     = blockIdx.x;
    const int xcd     = bid & 7;
    const int ii      = bid >> 3;
    const int fg      = ii & 7;                 // feature group (8 feats)
    const int rowtile = (xcd << 5) | (ii >> 3); // 0..255
    const int r0      = rowtile << 6;           // 64 rows per block

    const int tid  = threadIdx.x;
    const int lane = tid & 63;
    const int wv   = tid >> 6;     // wave = feature-in-group
    const int l15  = lane & 15;
    const int kg   = lane >> 4;
    const int f    = fg * 8 + wv;

    // ---- phase A: stage W1^T (8 features, bf16) ----
    {
        const float* src = W1 + (size_t)fg * 8 * 2048;
#pragma unroll
        for (int it = 0; it < 4; ++it) {
            int e0 = (it * 512 + tid) * 8;
            f32x4 v0 = *(const f32x4*)(src + e0);
            f32x4 v1 = *(const f32x4*)(src + e0 + 4);
#pragma unroll
            for (int j = 0; j < 8; ++j) {
                int e = e0 + j, f8 = e >> 11, r = e & 2047;
                float v = (j < 4) ? v0[j] : v1[j - 4];
                u_sm[(f8 << 11) | ((r & 63) << 5) | (r >> 6)] = f2bf(v);  // [f8][n<64][k<32]
            }
        }
    }
    __syncthreads();
    short8 w1b[4];
#pragma unroll
    for (int nt = 0; nt < 4; ++nt)
        w1b[nt] = *(const short8*)&u_sm[wv * 2048 + (nt * 16 + l15) * 32 + kg * 8];
    __syncthreads();

    // ---- phase B: stage W2^T ----
    {
        const float* src = W2 + (size_t)fg * 8 * 2048;
#pragma unroll
        for (int it = 0; it < 4; ++it) {
            int e0 = (it * 512 + tid) * 8;
            f32x4 v0 = *(const f32x4*)(src + e0);
            f32x4 v1 = *(const f32x4*)(src + e0 + 4);
#pragma unroll
            for (int j = 0; j < 8; ++j) {
                int e = e0 + j, f8 = e >> 11, r = e & 2047;
                float v = (j < 4) ? v0[j] : v1[j - 4];
                u_sm[(f8 << 11) | ((r & 31) << 6) | (r >> 5)] = f2bf(v);  // [f8][n<32][k<64]
            }
        }
    }
    __syncthreads();
    short8 w2b[2][2];
#pragma unroll
    for (int nt = 0; nt < 2; ++nt)
#pragma unroll
        for (int ks = 0; ks < 2; ++ks)
            w2b[nt][ks] = *(const short8*)&u_sm[wv * 2048 + (nt * 16 + l15) * 64 + ks * 32 + kg * 8];
    __syncthreads();

    float b1v[4], b2v[2];
#pragma unroll
    for (int nt = 0; nt < 4; ++nt) b1v[nt] = b1[f * 64 + nt * 16 + l15];
#pragma unroll
    for (int nt = 0; nt < 2; ++nt) b2v[nt] = b2[f * 32 + nt * 16 + l15];

    // per-feature card / local column offset (CARDS = [4,8,16,32]*8 ++ [1]*32)
    int card, offl;
    if (f < 32) { card = 4 << (wv & 3); offl = (wv >> 2) * 60 + card - 4; }
    else        { card = 1;             offl = wv; }

    unsigned short* hw = u_sm + 16384 + wv * 1024;   // wave-private h tile
    float* outl = (float*)u_sm;                      // [64][124] f32 gather tile
    const f32x4 zero = {0.f, 0.f, 0.f, 0.f};

    // ---- hoist all x loads (4 m-tiles x 2 dwordx4) for max MLP ----
    f32x4 xa[4][2];
#pragma unroll
    for (int t = 0; t < 4; ++t) {
        const float* xr = x + (size_t)(r0 + t * 16 + l15) * XROW + f * 32 + kg * 8;
        xa[t][0] = *(const f32x4*)xr;
        xa[t][1] = *(const f32x4*)(xr + 4);
    }

#pragma unroll
    for (int t = 0; t < 4; ++t) {
        short8 af;
#pragma unroll
        for (int j = 0; j < 4; ++j) {
            af[j]     = (short)f2bf(xa[t][0][j]);
            af[4 + j] = (short)f2bf(xa[t][1][j]);
        }

        // GEMM1: h[16x64] = x[16x32] @ W1[32x64]
        f32x4 c1[4];
#pragma unroll
        for (int nt = 0; nt < 4; ++nt)
            c1[nt] = __builtin_amdgcn_mfma_f32_16x16x32_bf16(af, w1b[nt], zero, 0, 0, 0);

        // bias + ReLU -> bf16 -> wave-private swizzled LDS (no barrier)
#pragma unroll
        for (int nt = 0; nt < 4; ++nt) {
#pragma unroll
            for (int j = 0; j < 4; ++j) {
                int r = kg * 4 + j;
                int c = nt * 16 + l15;
                float v = c1[nt][j] + b1v[nt];
                v = v > 0.f ? v : 0.f;
                hw[(r * 64 + c) ^ ((r & 7) << 3)] = f2bf(v);
            }
        }

        // GEMM2 A-fragments from swizzled LDS
        short8 ha[2];
#pragma unroll
        for (int ks = 0; ks < 2; ++ks)
            ha[ks] = *(const short8*)&hw[(l15 * 64 + ks * 32 + kg * 8) ^ ((l15 & 7) << 3)];

        // GEMM2: out[16x32] = h @ W2; skip n-tile 1 unless card==32
        f32x4 c2[2];
        c2[0] = __builtin_amdgcn_mfma_f32_16x16x32_bf16(ha[0], w2b[0][0], zero, 0, 0, 0);
        c2[0] = __builtin_amdgcn_mfma_f32_16x16x32_bf16(ha[1], w2b[0][1], c2[0], 0, 0, 0);
        if (card == 32) {
            c2[1] = __builtin_amdgcn_mfma_f32_16x16x32_bf16(ha[0], w2b[1][0], zero, 0, 0, 0);
            c2[1] = __builtin_amdgcn_mfma_f32_16x16x32_bf16(ha[1], w2b[1][1], c2[1], 0, 0, 0);
        }

        // deposit into out gather tile (disjoint columns per wave -> no race)
        const int ntiles = (card == 32) ? 2 : 1;
        for (int nt = 0; nt < ntiles; ++nt) {
            if (l15 < card) {
                float bias = b2v[nt];
#pragma unroll
                for (int j = 0; j < 4; ++j)
                    outl[(t * 16 + kg * 4 + j) * 124 + offl + nt * 16 + l15] = c2[nt][j] + bias;
            }
        }
    }
    __syncthreads();

    // ---- cooperative coalesced store of the gathered tile ----
    if (fg < 4) {
        // 64 rows x 120 floats -> 480-B contiguous chunks per row, full-line stores
#pragma unroll
        for (int it = 0; it < 4; ++it) {
            int c = tid + it * 512;
            if (c < 1920) {
                int row = c / 30, q = c - row * 30;
                f32x4 v = *(const f32x4*)&outl[row * 124 + q * 4];
                *(f32x4*)(out + (size_t)(r0 + row) * TOT_ + fg * 120 + q * 4) = v;
            }
        }
    } else {
        // 64 rows x 8 floats (numerical features, card=1)
        if (tid < 128) {
            int row = tid >> 1, half = tid & 1;
            f32x4 v = *(const f32x4*)&outl[row * 124 + half * 4];
            *(f32x4*)(out + (size_t)(r0 + row) * TOT_ + 480 + (fg - 4) * 8 + half * 4) = v;
        }
    }
}

extern "C" void kernel_launch(void* const* d_in, const int* in_sizes, int n_in,
                              void* d_out, int out_size, void* d_ws, size_t ws_size,
                              hipStream_t stream) {
    const float* x  = (const float*)d_in[0];
    const float* W1 = (const float*)d_in[1];
    const float* b1 = (const float*)d_in[2];
    const float* W2 = (const float*)d_in[3];
    const float* b2 = (const float*)d_in[4];
    float* out = (float*)d_out;
    recon_kernel<<<NB_, 512, 0, stream>>>(x, W1, b1, W2, b2, out);
}

// Round 3
// 39.609 us; speedup vs baseline: 1.3618x; 1.3618x over previous
//
#include <hip/hip_runtime.h>

typedef __attribute__((ext_vector_type(8))) short short8;
typedef __attribute__((ext_vector_type(4))) float f32x4;
typedef __attribute__((ext_vector_type(4))) unsigned short u16x4;

#define DI __device__ __forceinline__

namespace {
constexpr int TOT_ = 512;                 // output row width (floats)
constexpr int XROW = 2048;                // x row width (floats) = F*D
constexpr int BT_  = 256;                 // batch rows per block
constexpr int NB_  = (16384 / BT_) * 64;  // 4096 blocks
}

DI unsigned short f2bf(float v) {
    __bf16 h = (__bf16)v;                 // RNE convert
    return __builtin_bit_cast(unsigned short, h);
}

__global__ __launch_bounds__(256)
void recon_kernel(const float* __restrict__ x, const float* __restrict__ W1,
                  const float* __restrict__ b1, const float* __restrict__ W2,
                  const float* __restrict__ b2, float* __restrict__ out)
{
    __shared__ __align__(16) unsigned short w1t[64 * 32];    // [n<64][k<32]
    __shared__ __align__(16) unsigned short w2t[32 * 64];    // [n<32][k<64]
    __shared__ __align__(16) unsigned short hb[4][16 * 64];  // per-wave h^T tile

    // XCD-aware remap: per XCD, all 64 features of one 256-row tile are
    // co-resident -> full 8-KB x rows read together, out lines merge in L2.
    const int bid   = blockIdx.x;               // 0..4095
    const int f     = (bid >> 3) & 63;
    const int btile = ((bid & 7) << 3) | (bid >> 9);

    const int tid  = threadIdx.x;
    const int lane = tid & 63;
    const int wv   = tid >> 6;
    const int l15  = lane & 15;
    const int kg   = lane >> 4;
    const int swz  = (l15 & 7) << 3;            // XOR swizzle (16-B granule)

    // ---- stage W1^T and W2^T into LDS as bf16 (once per block) ----
    {
        const int e0 = tid * 8;                 // 256 thr x 8 = 2048 elements
        const float* W1f = W1 + f * 2048;
        const float* W2f = W2 + f * 2048;
        f32x4 v0 = *(const f32x4*)(W1f + e0);
        f32x4 v1 = *(const f32x4*)(W1f + e0 + 4);
        f32x4 u0 = *(const f32x4*)(W2f + e0);
        f32x4 u1 = *(const f32x4*)(W2f + e0 + 4);
#pragma unroll
        for (int j = 0; j < 8; ++j) {
            int e = e0 + j;
            float v = (j < 4) ? v0[j] : v1[j - 4];
            w1t[(e & 63) * 32 + (e >> 6)] = f2bf(v);   // W1: e = k*64 + n
            float u = (j < 4) ? u0[j] : u1[j - 4];
            w2t[(e & 31) * 64 + (e >> 5)] = f2bf(u);   // W2: e = k*32 + n
        }
    }
    __syncthreads();

    // ---- fragments (identical registers serve as swapped-A operands) ----
    short8 w1b[4];                               // W1[k][c] at lane: c=l15, k=kg*8+j
#pragma unroll
    for (int nt = 0; nt < 4; ++nt)
        w1b[nt] = *(const short8*)&w1t[(nt * 16 + l15) * 32 + kg * 8];

    short8 w2b[2][2];                            // W2[k][c] at lane: c=l15, k=ks*32+kg*8+j
#pragma unroll
    for (int nt = 0; nt < 2; ++nt)
#pragma unroll
        for (int ks = 0; ks < 2; ++ks)
            w2b[nt][ks] = *(const short8*)&w2t[(nt * 16 + l15) * 64 + ks * 32 + kg * 8];

    // biases along the per-lane column quad (c = nt*16 + kg*4 + j)
    f32x4 b1q[4], b2q[2];
#pragma unroll
    for (int nt = 0; nt < 4; ++nt) b1q[nt] = *(const f32x4*)(b1 + f * 64 + nt * 16 + kg * 4);
#pragma unroll
    for (int nt = 0; nt < 2; ++nt) b2q[nt] = *(const f32x4*)(b2 + f * 32 + nt * 16 + kg * 4);

    // output gather params (CARDS = [4,8,16,32]*8 ++ [1]*32)
    int card, off;
    if (f < 32) { card = 4 << (f & 3); off = (f >> 2) * 60 + card - 4; }
    else        { card = 1;            off = 480 + (f - 32); }

    unsigned short* hw = hb[wv];
    const f32x4 zero = {0.f, 0.f, 0.f, 0.f};
    const int b0 = btile * BT_ + wv * 64;

    // hoist all x loads (4 m-tiles x 2 dwordx4)
    f32x4 xa[4][2];
#pragma unroll
    for (int t = 0; t < 4; ++t) {
        const float* xr = x + (size_t)(b0 + t * 16 + l15) * XROW + f * 32 + kg * 8;
        xa[t][0] = *(const f32x4*)xr;
        xa[t][1] = *(const f32x4*)(xr + 4);
    }

#pragma unroll
    for (int t = 0; t < 4; ++t) {
        short8 af;                               // x[r][k] at lane: r=l15, k=kg*8+j
#pragma unroll
        for (int j = 0; j < 4; ++j) {
            af[j]     = (short)f2bf(xa[t][0][j]);
            af[4 + j] = (short)f2bf(xa[t][1][j]);
        }

        // GEMM1 swapped: C = W1^T @ x^T = h^T; lane holds h[c=nt*16+kg*4+j][r=l15]
        f32x4 c1[4];
#pragma unroll
        for (int nt = 0; nt < 4; ++nt)
            c1[nt] = __builtin_amdgcn_mfma_f32_16x16x32_bf16(w1b[nt], af, zero, 0, 0, 0);

        // bias + ReLU -> packed bf16x4 -> one ds_write_b64 per nt (swizzled)
#pragma unroll
        for (int nt = 0; nt < 4; ++nt) {
            u16x4 hv;
#pragma unroll
            for (int j = 0; j < 4; ++j) {
                float v = c1[nt][j] + b1q[nt][j];
                hv[j] = f2bf(v > 0.f ? v : 0.f);
            }
            *(u16x4*)&hw[(l15 * 64 + nt * 16 + kg * 4) ^ swz] = hv;
        }

        // GEMM2 A-fragments (h[r=l15][k=ks*32+kg*8+j]) from swizzled LDS
        short8 ha[2];
#pragma unroll
        for (int ks = 0; ks < 2; ++ks)
            ha[ks] = *(const short8*)&hw[(l15 * 64 + ks * 32 + kg * 8) ^ swz];

        // GEMM2 swapped: C = W2^T @ h^T = out^T; lane holds out[c=nt*16+kg*4+j][r=l15]
        f32x4 c2[2];
        c2[0] = __builtin_amdgcn_mfma_f32_16x16x32_bf16(w2b[0][0], ha[0], zero, 0, 0, 0);
        c2[0] = __builtin_amdgcn_mfma_f32_16x16x32_bf16(w2b[0][1], ha[1], c2[0], 0, 0, 0);
        if (card == 32) {
            c2[1] = __builtin_amdgcn_mfma_f32_16x16x32_bf16(w2b[1][0], ha[0], zero, 0, 0, 0);
            c2[1] = __builtin_amdgcn_mfma_f32_16x16x32_bf16(w2b[1][1], ha[1], c2[1], 0, 0, 0);
        }

        // store: each lane writes 4 consecutive floats (one dwordx4), 16-B aligned
        const int row = b0 + t * 16 + l15;
        if (card > 1) {
            const int ntiles = (card == 32) ? 2 : 1;
            for (int nt = 0; nt < ntiles; ++nt) {
                if (kg * 4 < card - nt * 16) {
                    f32x4 v;
#pragma unroll
                    for (int j = 0; j < 4; ++j) v[j] = c2[nt][j] + b2q[nt][j];
                    *(f32x4*)(out + (size_t)row * TOT_ + off + nt * 16 + kg * 4) = v;
                }
            }
        } else {
            if (kg == 0)
                out[(size_t)row * TOT_ + off] = c2[0][0] + b2q[0][0];
        }
    }
}

extern "C" void kernel_launch(void* const* d_in, const int* in_sizes, int n_in,
                              void* d_out, int out_size, void* d_ws, size_t ws_size,
                              hipStream_t stream) {
    const float* x  = (const float*)d_in[0];
    const float* W1 = (const float*)d_in[1];
    const float* b1 = (const float*)d_in[2];
    const float* W2 = (const float*)d_in[3];
    const float* b2 = (const float*)d_in[4];
    float* out = (float*)d_out;
    recon_kernel<<<NB_, 256, 0, stream>>>(x, W1, b1, W2, b2, out);
}